// Round 5
// baseline (462.613 us; speedup 1.0000x reference)
//
#include <hip/hip_runtime.h>
#include <math.h>

// Fused CNN classifier: conv(1->8,3x3,s2,p1)+ReLU -> conv(8->16,3x3,s2,p1)+ReLU
//                       -> FC(784->1) -> softplus+0.001 -> 1-exp(-r) -> clip
// B=65536 images of 1x28x28 fp32.
//
// R5 (= R4 with compile fix: manual RNE f2bf instead of __hip_bfloat162
// bit_cast, which is not trivially copyable on this ROCm).
//
// conv2+FC via bf16 MFMA implicit GEMM (conv2 = 79% of MACs; fp32 VALU
// floor is ~100us, MFMA moves it to the matrix pipe). One wave = one image:
//   z2[16 c2][49 pos] = W2mat[16][72(->96)] . z1col[96][49(->64)]
//   = 4 N-tiles x 3 K-steps of mfma_f32_16x16x32_bf16, fp32 accum.
// conv1 stays fp32 VALU (its im2col build would cost as much as computing it).
// z1 LDS layout [16 row][16+2 col][8 ch] bf16: conv1 writes 1 ds_write_b128
// per position; B-frag element address = posoff(lane%16) + offk(lane/16,j),
// separable -> offk precomputed once per block (persistent grid-stride).
// K-padding handled on the A side (W2 frag=0 for k>=72) so out-of-range B
// reads may be garbage-but-in-bounds. bf16 err ~1e-3 << 1.55e-2 threshold.

typedef short bf16x8 __attribute__((ext_vector_type(8)));
typedef float f32x4  __attribute__((ext_vector_type(4)));

#define NBLOCKS 4096
#define Z1_ROWSLOT 18              // col slots per z1 row (16 used + 2 pad)

static __device__ __forceinline__ short f2bf(float f) {
    union { float f; unsigned u; } v; v.f = f;
    unsigned r = v.u + 0x7FFF + ((v.u >> 16) & 1);   // RNE (no NaN inputs)
    return (short)(r >> 16);
}

__global__ __launch_bounds__(256, 2) void fused_cnn_mfma(
    const float* __restrict__ x,
    const float* __restrict__ W1, const float* __restrict__ b1,
    const float* __restrict__ W2, const float* __restrict__ b2,
    const float* __restrict__ Wfc, const float* __restrict__ bfc,
    float* __restrict__ out, int nimg)
{
    // Per image slot: padded input 30x31 f32 (borders stay zero across the
    // persistent loop; interior fully rewritten each staging).
    __shared__ float  simg[4][30 * 31];                 // 3720 B each
    __shared__ bf16x8 sz1[4][16 * Z1_ROWSLOT];          // 4608 B each

    const int tid  = threadIdx.x;
    const int w    = tid >> 6;       // wave id = image slot
    const int lane = tid & 63;
    const int hi   = lane >> 4;
    const int lo   = lane & 15;

    // ---------------- one-time setup ----------------
    for (int i = tid; i < 4 * 30 * 31; i += 256) ((float*)simg)[i] = 0.f;
    {
        bf16x8 zz = {0,0,0,0,0,0,0,0};
        for (int i = tid; i < 4 * 16 * Z1_ROWSLOT; i += 256) ((bf16x8*)sz1)[i] = zz;
    }

    // B-frag k-offsets (units: shorts) into z1 region.
    // z1 short index = row*144 + col*8 + ic, row=2qy+ty, col=2qx+tx
    //   -> posoff = qy*288 + qx*16 ; offk = ty*144 + tx*8 + ic
    int offk[24];
    #pragma unroll
    for (int kk = 0; kk < 3; kk++)
        #pragma unroll
        for (int j = 0; j < 8; j++) {
            int k = kk * 32 + hi * 8 + j;
            int off = 0;                           // k>=72: in-bounds dummy (A=0)
            if (k < 72) {
                int ic = k / 9, tap = k - ic * 9;
                int ty = tap / 3, tx = tap - ty * 3;
                off = ty * 144 + tx * 8 + ic;
            }
            offk[kk * 8 + j] = off;
        }

    // A-frags: W2 as bf16, rows m=lo (c2), k zero-padded 72->96.
    bf16x8 aW2[3];
    #pragma unroll
    for (int kk = 0; kk < 3; kk++)
        #pragma unroll
        for (int j = 0; j < 8; j++) {
            int k = kk * 32 + hi * 8 + j;
            float v = (k < 72) ? W2[lo * 72 + k] : 0.f;
            aW2[kk][j] = f2bf(v);
        }

    // N-tile position offsets (shorts). pos = t*16+lo; >=49 clamped (masked
    // later via wfcv=0 -- values only need to be finite & in-bounds).
    int posoff[4];
    #pragma unroll
    for (int t = 0; t < 4; t++) {
        int p = t * 16 + lo; if (p > 48) p = 48;
        int qy = p / 7, qx = p - qy * 7;
        posoff[t] = qy * 288 + qx * 16;
    }

    // Epilogue constants: C/D layout row=hi*4+r (c2), col=lo; pos=t*16+lo.
    float wfcv[4][4], b2v[4];
    #pragma unroll
    for (int r = 0; r < 4; r++) b2v[r] = b2[hi * 4 + r];
    #pragma unroll
    for (int t = 0; t < 4; t++)
        #pragma unroll
        for (int r = 0; r < 4; r++) {
            int p = t * 16 + lo;
            wfcv[t][r] = (p < 49) ? Wfc[(hi * 4 + r) * 49 + p] : 0.f;
        }
    const float bfc0 = bfc[0];

    const int nquad = (nimg + 3) >> 2;
    const short* __restrict__ zs = (const short*)&sz1[w][0];

    for (int q = blockIdx.x; q < nquad; q += gridDim.x) {
        __syncthreads();        // previous iteration's LDS reads done

        // ---- stage 4 images (784 float4, coalesced) ----
        {
            const float4* src = (const float4*)(x + (size_t)q * (4 * 784));
            for (int f = tid; f < 784; f += 256) {
                int im = f / 196, p4 = f - im * 196;
                if (q * 4 + im < nimg) {
                    float4 v = src[f];
                    int yy = p4 / 7, xx = (p4 - yy * 7) * 4;
                    float* d = &simg[im][(yy + 1) * 31 + xx + 1];
                    d[0] = v.x; d[1] = v.y; d[2] = v.z; d[3] = v.w;
                }
            }
        }
        __syncthreads();

        // ---- conv1 (fp32 VALU) for image q*4+w; write z1 as bf16x8 ----
        #pragma unroll
        for (int i = 0; i < 4; i++) {
            int p = i * 64 + lane;
            bool valid = (p < 196);
            int pc = valid ? p : 195;
            int py = pc / 14, px = pc - py * 14;
            const float* wb = &simg[w][(2 * py) * 31 + 2 * px];
            float t0 = wb[0],  t1 = wb[1],  t2 = wb[2];
            float t3 = wb[31], t4 = wb[32], t5 = wb[33];
            float t6 = wb[62], t7 = wb[63], t8 = wb[64];
            asm volatile("" : "+v"(t0), "+v"(t1), "+v"(t2), "+v"(t3), "+v"(t4),
                              "+v"(t5), "+v"(t6), "+v"(t7), "+v"(t8));
            bf16x8 zr;
            #pragma unroll
            for (int c = 0; c < 8; c += 2) {
                const float* wa = &W1[c * 9];
                const float* wc = &W1[(c + 1) * 9];
                float za = b1[c], zb = b1[c + 1];
                za = fmaf(t0, wa[0], za); zb = fmaf(t0, wc[0], zb);
                za = fmaf(t1, wa[1], za); zb = fmaf(t1, wc[1], zb);
                za = fmaf(t2, wa[2], za); zb = fmaf(t2, wc[2], zb);
                za = fmaf(t3, wa[3], za); zb = fmaf(t3, wc[3], zb);
                za = fmaf(t4, wa[4], za); zb = fmaf(t4, wc[4], zb);
                za = fmaf(t5, wa[5], za); zb = fmaf(t5, wc[5], zb);
                za = fmaf(t6, wa[6], za); zb = fmaf(t6, wc[6], zb);
                za = fmaf(t7, wa[7], za); zb = fmaf(t7, wc[7], zb);
                za = fmaf(t8, wa[8], za); zb = fmaf(t8, wc[8], zb);
                za = fmaxf(za, 0.f);      zb = fmaxf(zb, 0.f);
                zr[c]     = f2bf(za);
                zr[c + 1] = f2bf(zb);
            }
            if (valid) sz1[w][(py + 1) * Z1_ROWSLOT + (px + 1)] = zr;
        }
        // No barrier: z1 is wave-private; compiler inserts lgkmcnt waits.

        // ---- conv2: 4 N-tiles x 3 K-steps MFMA ----
        f32x4 acc[4];
        {
            f32x4 z4 = {0.f, 0.f, 0.f, 0.f};
            #pragma unroll
            for (int t = 0; t < 4; t++) acc[t] = z4;
        }
        #pragma unroll
        for (int t = 0; t < 4; t++) {
            #pragma unroll
            for (int kk = 0; kk < 3; kk++) {
                bf16x8 bf;
                #pragma unroll
                for (int j = 0; j < 8; j++)
                    bf[j] = zs[posoff[t] + offk[kk * 8 + j]];
                acc[t] = __builtin_amdgcn_mfma_f32_16x16x32_bf16(
                             aW2[kk], bf, acc[t], 0, 0, 0);
            }
        }

        // ---- epilogue: bias+ReLU+FC fold, wave reduce, softplus ----
        float fc = 0.f;
        #pragma unroll
        for (int t = 0; t < 4; t++)
            #pragma unroll
            for (int r = 0; r < 4; r++) {
                float z = fmaxf(acc[t][r] + b2v[r], 0.f);
                fc = fmaf(z, wfcv[t][r], fc);
            }
        #pragma unroll
        for (int off = 32; off > 0; off >>= 1)
            fc += __shfl_down(fc, off, 64);

        if (lane == 0) {
            int img = q * 4 + w;
            if (img < nimg) {
                float v    = fc + bfc0;
                float sp   = fmaxf(v, 0.f) + log1pf(expf(-fabsf(v)));
                float rate = sp + 0.001f;
                float pr   = 1.f - expf(-rate);
                out[img] = fminf(fmaxf(pr, 1e-6f), 1.f - 1e-6f);
            }
        }
    }
}

extern "C" void kernel_launch(void* const* d_in, const int* in_sizes, int n_in,
                              void* d_out, int out_size, void* d_ws, size_t ws_size,
                              hipStream_t stream) {
    const float* x   = (const float*)d_in[0];
    const float* W1  = (const float*)d_in[1];
    const float* b1  = (const float*)d_in[2];
    const float* W2  = (const float*)d_in[3];
    const float* b2  = (const float*)d_in[4];
    const float* Wfc = (const float*)d_in[5];
    const float* bfc = (const float*)d_in[6];
    float* out = (float*)d_out;

    const int nimg  = in_sizes[0] / 784;
    const int nquad = (nimg + 3) / 4;
    const int grid  = nquad < NBLOCKS ? nquad : NBLOCKS;

    fused_cnn_mfma<<<grid, 256, 0, stream>>>(x, W1, b1, W2, b2, Wfc, bfc,
                                             out, nimg);
}

// Round 6
// 354.406 us; speedup vs baseline: 1.3053x; 1.3053x over previous
//
#include <hip/hip_runtime.h>
#include <math.h>

// Fused CNN classifier: conv(1->8,3x3,s2,p1)+ReLU -> conv(8->16,3x3,s2,p1)+ReLU
//                       -> FC(784->1) -> softplus+0.001 -> 1-exp(-r) -> clip
// B=65536 images of 1x28x28 fp32.
//
// R6: R5's B-frag gather (96 ds_read_u16/img, 5.1e7 bank-conflict cycles) was
// the bottleneck. Fix: choose im2col K-order k = tap*8+ic so each aligned
// 8-k group = one position's 8 contiguous bf16 channels, and SWAP operand
// roles: A = z1 im2col (frag read = ONE ds_read_b128), B = W2 in registers
// (precomputed; k>=72 zeroed on B side so pad-k A garbage contributes 0).
// z1 layout [15 rows][19 slots][8ch bf16]; stride 19 (odd) balances bank
// groups: per b128 read exactly 8 lanes/slot-group = near-minimal cost.
// D layout: lane(hi,lo) holds D[pos = hi*4+r (within tile)][c2 = lo].
// 12 ds_read_b128 + 12 MFMA per image. conv1 stays fp32 VALU.

typedef short bf16x8 __attribute__((ext_vector_type(8)));
typedef float f32x4  __attribute__((ext_vector_type(4)));

#define NBLOCKS 4096
#define Z1_RS 19                    // z1 row stride in 16B slots (odd!)
#define Z1_SLOTS (15 * Z1_RS)       // 285 slots per image

static __device__ __forceinline__ short f2bf(float f) {
    union { float f; unsigned u; } v; v.f = f;
    unsigned r = v.u + 0x7FFF + ((v.u >> 16) & 1);   // RNE (no NaN inputs)
    return (short)(r >> 16);
}

__global__ __launch_bounds__(256, 4) void fused_cnn_mfma(
    const float* __restrict__ x,
    const float* __restrict__ W1, const float* __restrict__ b1,
    const float* __restrict__ W2, const float* __restrict__ b2,
    const float* __restrict__ Wfc, const float* __restrict__ bfc,
    float* __restrict__ out, int nimg)
{
    __shared__ float  simg[4][30 * 31];        // padded input, 3720 B/slot
    __shared__ bf16x8 sz1[4][Z1_SLOTS];        // z1, 4560 B/slot

    const int tid  = threadIdx.x;
    const int w    = tid >> 6;       // wave id = image slot
    const int lane = tid & 63;
    const int hi   = lane >> 4;
    const int lo   = lane & 15;

    // ---------------- one-time setup ----------------
    for (int i = tid; i < 4 * 30 * 31; i += 256) ((float*)simg)[i] = 0.f;
    {
        bf16x8 zz = {0,0,0,0,0,0,0,0};
        for (int i = tid; i < 4 * Z1_SLOTS; i += 256) ((bf16x8*)sz1)[i] = zz;
    }

    // B-frags: W2 as bf16 in registers. k = tap*8 + ic; lane(hi,lo):
    // B[k=kk*32+hi*8+j][n=lo] -> tap = kk*4+hi, ic=j. tap>=9 => 0 (K-pad).
    bf16x8 wb[3];
    #pragma unroll
    for (int kk = 0; kk < 3; kk++) {
        const int tap = kk * 4 + hi;
        #pragma unroll
        for (int j = 0; j < 8; j++)
            wb[kk][j] = (tap < 9) ? f2bf(W2[lo * 72 + j * 9 + tap])
                                  : (short)0;
    }

    // A-read byte offsets into sz1[w]: slot = (2qy+ty)*19 + (2qx+tx)
    // (z1 coord c stored at index c+1; borders stay zero).
    int posoff[4];                  // from pos = t*16+lo  (clamped >48)
    #pragma unroll
    for (int t = 0; t < 4; t++) {
        int p = t * 16 + lo; if (p > 48) p = 48;
        int qy = p / 7, qx = p - qy * 7;
        posoff[t] = ((2 * qy) * Z1_RS + 2 * qx) * 16;
    }
    int tapoff[3];                  // from tap = kk*4+hi (invalid -> 0)
    #pragma unroll
    for (int kk = 0; kk < 3; kk++) {
        int tap = kk * 4 + hi;
        int ty = tap / 3, tx = tap - ty * 3;
        tapoff[kk] = (tap < 9) ? (ty * Z1_RS + tx) * 16 : 0;
    }

    // Epilogue constants: lane(hi,lo) holds D[pos=t*16+hi*4+r][c2=lo].
    const float b2v = b2[lo];
    float wfc[4][4];
    #pragma unroll
    for (int t = 0; t < 4; t++)
        #pragma unroll
        for (int r = 0; r < 4; r++) {
            int p = t * 16 + hi * 4 + r;
            wfc[t][r] = (p < 49) ? Wfc[lo * 49 + p] : 0.f;
        }
    const float bfc0 = bfc[0];

    const int nquad = (nimg + 3) >> 2;
    const char* __restrict__ zb = (const char*)&sz1[w][0];

    for (int q = blockIdx.x; q < nquad; q += gridDim.x) {
        __syncthreads();        // previous iteration's simg reads done

        // ---- stage 4 images (784 float4, coalesced) ----
        {
            const float4* src = (const float4*)(x + (size_t)q * (4 * 784));
            for (int f = tid; f < 784; f += 256) {
                int im = f / 196, p4 = f - im * 196;
                if (q * 4 + im < nimg) {
                    float4 v = src[f];
                    int yy = p4 / 7, xx = (p4 - yy * 7) * 4;
                    float* d = &simg[im][(yy + 1) * 31 + xx + 1];
                    d[0] = v.x; d[1] = v.y; d[2] = v.z; d[3] = v.w;
                }
            }
        }
        __syncthreads();

        // ---- conv1 (fp32 VALU) for image q*4+w; write z1 bf16x8 ----
        #pragma unroll
        for (int i = 0; i < 4; i++) {
            int p = i * 64 + lane;
            bool valid = (p < 196);
            int pc = valid ? p : 195;
            int py = pc / 14, px = pc - py * 14;
            const float* wbse = &simg[w][(2 * py) * 31 + 2 * px];
            float t0 = wbse[0],  t1 = wbse[1],  t2 = wbse[2];
            float t3 = wbse[31], t4 = wbse[32], t5 = wbse[33];
            float t6 = wbse[62], t7 = wbse[63], t8 = wbse[64];
            asm volatile("" : "+v"(t0), "+v"(t1), "+v"(t2), "+v"(t3), "+v"(t4),
                              "+v"(t5), "+v"(t6), "+v"(t7), "+v"(t8));
            bf16x8 zr;
            #pragma unroll
            for (int c = 0; c < 8; c += 2) {
                const float* wa = &W1[c * 9];
                const float* wc = &W1[(c + 1) * 9];
                float za = b1[c], zc = b1[c + 1];
                za = fmaf(t0, wa[0], za); zc = fmaf(t0, wc[0], zc);
                za = fmaf(t1, wa[1], za); zc = fmaf(t1, wc[1], zc);
                za = fmaf(t2, wa[2], za); zc = fmaf(t2, wc[2], zc);
                za = fmaf(t3, wa[3], za); zc = fmaf(t3, wc[3], zc);
                za = fmaf(t4, wa[4], za); zc = fmaf(t4, wc[4], zc);
                za = fmaf(t5, wa[5], za); zc = fmaf(t5, wc[5], zc);
                za = fmaf(t6, wa[6], za); zc = fmaf(t6, wc[6], zc);
                za = fmaf(t7, wa[7], za); zc = fmaf(t7, wc[7], zc);
                za = fmaf(t8, wa[8], za); zc = fmaf(t8, wc[8], zc);
                za = fmaxf(za, 0.f);      zc = fmaxf(zc, 0.f);
                zr[c]     = f2bf(za);
                zr[c + 1] = f2bf(zc);
            }
            if (valid) sz1[w][(py + 1) * Z1_RS + (px + 1)] = zr;
        }
        // z1 is wave-private: no barrier (compiler inserts lgkmcnt waits).

        // ---- conv2: 4 pos-tiles x 3 K-steps; A = z1 (one b128/frag) ----
        f32x4 acc[4];
        {
            f32x4 z4 = {0.f, 0.f, 0.f, 0.f};
            #pragma unroll
            for (int t = 0; t < 4; t++) acc[t] = z4;
        }
        #pragma unroll
        for (int t = 0; t < 4; t++) {
            #pragma unroll
            for (int kk = 0; kk < 3; kk++) {
                bf16x8 af = *(const bf16x8*)(zb + posoff[t] + tapoff[kk]);
                acc[t] = __builtin_amdgcn_mfma_f32_16x16x32_bf16(
                             af, wb[kk], acc[t], 0, 0, 0);
            }
        }

        // ---- epilogue: bias+ReLU+FC fold, wave reduce, softplus ----
        float fc = 0.f;
        #pragma unroll
        for (int t = 0; t < 4; t++)
            #pragma unroll
            for (int r = 0; r < 4; r++) {
                float z = fmaxf(acc[t][r] + b2v, 0.f);
                fc = fmaf(z, wfc[t][r], fc);
            }
        #pragma unroll
        for (int off = 32; off > 0; off >>= 1)
            fc += __shfl_down(fc, off, 64);

        if (lane == 0) {
            int img = q * 4 + w;
            if (img < nimg) {
                float v    = fc + bfc0;
                float sp   = fmaxf(v, 0.f) + log1pf(expf(-fabsf(v)));
                float rate = sp + 0.001f;
                float pr   = 1.f - expf(-rate);
                out[img] = fminf(fmaxf(pr, 1e-6f), 1.f - 1e-6f);
            }
        }
    }
}

extern "C" void kernel_launch(void* const* d_in, const int* in_sizes, int n_in,
                              void* d_out, int out_size, void* d_ws, size_t ws_size,
                              hipStream_t stream) {
    const float* x   = (const float*)d_in[0];
    const float* W1  = (const float*)d_in[1];
    const float* b1  = (const float*)d_in[2];
    const float* W2  = (const float*)d_in[3];
    const float* b2  = (const float*)d_in[4];
    const float* Wfc = (const float*)d_in[5];
    const float* bfc = (const float*)d_in[6];
    float* out = (float*)d_out;

    const int nimg  = in_sizes[0] / 784;
    const int nquad = (nimg + 3) / 4;
    const int grid  = nquad < NBLOCKS ? nquad : NBLOCKS;

    fused_cnn_mfma<<<grid, 256, 0, stream>>>(x, W1, b1, W2, b2, Wfc, bfc,
                                             out, nimg);
}